// Round 11
// baseline (609.492 us; speedup 1.0000x reference)
//
#include <hip/hip_runtime.h>
#include <cstdint>
#include <cstddef>

// ---------------------------------------------------------------------------
// PointNetFeaturePropagation: 3-NN interpolation + Linear + BatchNorm1d
// B=4 N=16384 S=4096 D=64
//
// R8 = FIRST MEASUREMENT: total 430us, K1 knn_interp = 286us (2/3 of total),
// VALUBusy 22.8%, VGPR 32, Occupancy 23%, HBM 1.4% -> LATENCY-BOUND.
// Root cause: per-candidate __any branch fragments the loop into basic
// blocks; compiler issues ONE load per iteration (VGPR=32 proves no
// prefetch window) -> ~300cy exposed L2 latency per candidate.
//
// R9-R11 fix (benches R9/R10 lost to infra; resubmitted UNCHANGED to keep
// the single-hypothesis attribution clean):
//  - Manual ping-pong register prefetch: two named groups of 8 float4s;
//    loads of the next group are issued in straight-line code BEFORE the
//    branchy processing of the current group -> latency hidden under
//    ~136cy of compute + 4-wave TLP. Named regs = static indexing (no
//    scratch). AMDGPU scheduler does not sink loads across control flow,
//    so the issue slots stay ahead of the branches.
//  - Lane-quad layout: 4 lanes/query scan 1024 cands each -> 4096 waves
//    = 4 waves/SIMD (was 2). 2-round shfl_xor merge in ascending-chunk
//    order preserves exact jax.lax.top_k lowest-index tie-break.
//  - Early-out KEPT (wave-joint taken fraction ~0.19): branches sit
//    between load-issue and load-use, so they no longer serialize loads.
//  - Key arithmetic FROZEN byte-for-byte (absmax 0.03125 passed).
// K0/K3/K4 frozen from R7 to attribute the delta.
// Predicted: K1 50-70us (VALUBusy 60-80%, VGPR ~100-128, Occ ~45%),
// total ~190-215us.
// Post-mortem plan: VALUBusy<40% & VGPR~32 -> compiler sank loads ->
// global_load_lds staging or asm. VALUBusy high & >80us -> drop branch.
// ---------------------------------------------------------------------------

#define BB 4
#define NN 16384
#define SS 4096
#define DD 64
#define TQ (BB * NN)          // 65536 queries
#define CH (SS / 4)           // 1024 candidates per lane of a quad
#define FLT_BIG 3.4028235e38f

// Branchless top-3 insert; strict '<' keeps first-seen on ties (matches
// jax.lax.top_k tie-break = lowest index, given insertion in index order).
static __device__ __forceinline__ void ins3(float dd, int ii,
                                            float& d0, float& d1, float& d2,
                                            int& i0, int& i1, int& i2) {
  bool l0 = dd < d0, l1 = dd < d1, l2 = dd < d2;
  d2 = l1 ? d1 : (l2 ? dd : d2);  i2 = l1 ? i1 : (l2 ? ii : i2);
  d1 = l0 ? d0 : (l1 ? dd : d1);  i1 = l0 ? i0 : (l1 ? ii : i1);
  d0 = l0 ? dd : d0;              i0 = l0 ? ii : i0;
}

// K0: build (x, y, z, |p|^2) float4 per xyz2 point; zero BN accumulators.
__global__ __launch_bounds__(256) void prep(const float* __restrict__ xyz2,
                                            float4* __restrict__ pts4,
                                            float* __restrict__ accum) {
  const int i = (int)blockIdx.x * 256 + (int)threadIdx.x;  // 16384 points total
  if (blockIdx.x == 0 && threadIdx.x < 128) accum[threadIdx.x] = 0.0f;
  float x = xyz2[3 * i], y = xyz2[3 * i + 1], z = xyz2[3 * i + 2];
  float p2 = __fadd_rn(__fadd_rn(__fmul_rn(x, x), __fmul_rn(y, y)), __fmul_rn(z, z));
  pts4[i] = make_float4(x, y, z, p2);
}

// K1 (fused): 3-NN + inverse-distance interpolation, lane-quad layout with
// ping-pong register prefetch. Key d with EXACT reference rounding (frozen):
//   dot = fma(qz,pz, fma(qy,py, mul(qx,px)));  d = fma(-2, dot, add(q2,p2))
__global__ __launch_bounds__(256, 4) void knn_interp(const float* __restrict__ xyz1,
                                                     const float4* __restrict__ pts4,
                                                     const float* __restrict__ points2,
                                                     float* __restrict__ interp) {
  const int lane  = (int)threadIdx.x & 63;
  const int gw    = (int)blockIdx.x * 4 + ((int)threadIdx.x >> 6);  // 0..4095
  const int q     = gw * 16 + (lane >> 2);   // 16 queries per wave
  const int chunk = lane & 3;                // quad lane c scans chunk c
  // 16-aligned query spans never cross a batch boundary; SGPR residency
  const int batch = __builtin_amdgcn_readfirstlane(q >> 14);

  const float qx = xyz1[3 * q], qy = xyz1[3 * q + 1], qz = xyz1[3 * q + 2];
  const float q2 = __fadd_rn(__fadd_rn(__fmul_rn(qx, qx), __fmul_rn(qy, qy)), __fmul_rn(qz, qz));
  const float4* __restrict__ cp = pts4 + (size_t)batch * SS + (size_t)chunk * CH;

  float d0 = FLT_BIG, d1 = FLT_BIG, d2v = FLT_BIG;
  int j0 = 0, j1 = 0, j2 = 0;

#define PROC(P, IDX) do {                                                      \
    float dot_ = __fmaf_rn(qz, (P).z, __fmaf_rn(qy, (P).y, __fmul_rn(qx, (P).x))); \
    float dd_  = __fmaf_rn(-2.0f, dot_, __fadd_rn(q2, (P).w));                 \
    if (__any(dd_ < d2v)) ins3(dd_, (IDX), d0, d1, d2v, j0, j1, j2);           \
  } while (0)

#define LD8(R, base)                                                           \
    R##0 = cp[(base) + 0]; R##1 = cp[(base) + 1];                              \
    R##2 = cp[(base) + 2]; R##3 = cp[(base) + 3];                              \
    R##4 = cp[(base) + 4]; R##5 = cp[(base) + 5];                              \
    R##6 = cp[(base) + 6]; R##7 = cp[(base) + 7];

#define PR8(R, base)                                                           \
    PROC(R##0, (base) + 0); PROC(R##1, (base) + 1);                            \
    PROC(R##2, (base) + 2); PROC(R##3, (base) + 3);                            \
    PROC(R##4, (base) + 4); PROC(R##5, (base) + 5);                            \
    PROC(R##6, (base) + 6); PROC(R##7, (base) + 7);

  float4 a0, a1, a2, a3, a4, a5, a6, a7;
  float4 b0, b1, b2, b3, b4, b5, b6, b7;

  LD8(a, 0)                        // prologue: group [0,8)
  int s = 0;
  for (; s < CH - 16; s += 16) {   // body invariant: A holds [s, s+8)
    LD8(b, s + 8)                  // issue next loads BEFORE branchy compute
    PR8(a, s)                      // branches run while B-loads fly
    LD8(a, s + 16)
    PR8(b, s + 8)
  }
  // s == CH-16: A holds [s, s+8)
  LD8(b, s + 8)
  PR8(a, s)
  PR8(b, s + 8)

#undef PROC
#undef LD8
#undef PR8

  // globalize indices within the batch (chunk c covers [c*CH, (c+1)*CH))
  const int cbase = chunk << 10;
  j0 += cbase; j1 += cbase; j2 += cbase;

  // quad merge, ascending-chunk order preserves top_k tie-break.
  // Round 1 (xor 1): even-chunk lane of each pair merges correctly
  // (partner items all higher-index, strict '<' ranks them after).
  {
    float e0 = __shfl_xor(d0, 1, 64), e1 = __shfl_xor(d1, 1, 64), e2 = __shfl_xor(d2v, 1, 64);
    int   k0 = __shfl_xor(j0, 1, 64), k1 = __shfl_xor(j1, 1, 64), k2 = __shfl_xor(j2, 1, 64);
    ins3(e0, k0, d0, d1, d2v, j0, j1, j2);
    ins3(e1, k1, d0, d1, d2v, j0, j1, j2);
    ins3(e2, k2, d0, d1, d2v, j0, j1, j2);
  }
  // Round 2 (xor 2): lane (quad&3)==0 pulls lane+2's merged triple
  // (chunks {2,3}, all higher-index than {0,1}).
  {
    float e0 = __shfl_xor(d0, 2, 64), e1 = __shfl_xor(d1, 2, 64), e2 = __shfl_xor(d2v, 2, 64);
    int   k0 = __shfl_xor(j0, 2, 64), k1 = __shfl_xor(j1, 2, 64), k2 = __shfl_xor(j2, 2, 64);
    ins3(e0, k0, d0, d1, d2v, j0, j1, j2);
    ins3(e1, k1, d0, d1, d2v, j0, j1, j2);
    ins3(e2, k2, d0, d1, d2v, j0, j1, j2);
  }
  // broadcast the quad leader's merged result to all 4 lanes
  {
    const int src = lane & ~3;
    d0  = __shfl(d0, src, 64);  d1 = __shfl(d1, src, 64);  d2v = __shfl(d2v, src, 64);
    j0  = __shfl(j0, src, 64);  j1 = __shfl(j1, src, 64);  j2  = __shfl(j2, src, 64);
  }

  // weights: 1/(d+1e-8) (IEEE div), normalized by true div — reference order
  float r0 = 1.0f / __fadd_rn(d0, 1e-8f);
  float r1 = 1.0f / __fadd_rn(d1, 1e-8f);
  float r2 = 1.0f / __fadd_rn(d2v, 1e-8f);
  float rs = __fadd_rn(__fadd_rn(r0, r1), r2);
  float w0 = r0 / rs, w1 = r1 / rs, w2 = r2 / rs;

  // gather + blend: quad splits the 16 float4s of the row (4 each)
  const float* p2b = points2 + (size_t)batch * SS * DD;
  const float4* g0 = (const float4*)(p2b + (size_t)j0 * DD);
  const float4* g1 = (const float4*)(p2b + (size_t)j1 * DD);
  const float4* g2 = (const float4*)(p2b + (size_t)j2 * DD);
  float4* op = (float4*)(interp + (size_t)q * DD);
  const int kb = chunk << 2;
#pragma unroll
  for (int k = 0; k < 4; ++k) {
    const int kk = kb + k;
    float4 a = g0[kk], b = g1[kk], c = g2[kk], r;
    // sum over the 3-neighbor axis: ((g0*w0 + g1*w1) + g2*w2), XLA reduce order
    r.x = __fadd_rn(__fadd_rn(__fmul_rn(a.x, w0), __fmul_rn(b.x, w1)), __fmul_rn(c.x, w2));
    r.y = __fadd_rn(__fadd_rn(__fmul_rn(a.y, w0), __fmul_rn(b.y, w1)), __fmul_rn(c.y, w2));
    r.z = __fadd_rn(__fadd_rn(__fmul_rn(a.z, w0), __fmul_rn(b.z, w1)), __fmul_rn(c.z, w2));
    r.w = __fadd_rn(__fadd_rn(__fmul_rn(a.w, w0), __fmul_rn(b.w, w1)), __fmul_rn(c.w, w2));
    op[kk] = r;
  }
}

// K3: Linear out[q][e] = sum_d interp[q][d] * W[e][d] + b[e].  lane = e;
// W row in VGPRs; interp row addresses wave-uniform. BN sum/sumsq atomics.
#define K3_BODY(QUAL)                                                          \
  const int lane = (int)threadIdx.x & 63;                                      \
  int gw = (int)blockIdx.x * 4 + ((int)threadIdx.x >> 6); /* 0..2047 */        \
  gw = __builtin_amdgcn_readfirstlane(gw);                                     \
  float wreg[DD];                                                              \
  const float4* wr = (const float4*)(W + (size_t)lane * DD);                   \
  _Pragma("unroll")                                                            \
  for (int k = 0; k < DD / 4; ++k) {                                           \
    float4 t = wr[k];                                                          \
    wreg[4 * k] = t.x; wreg[4 * k + 1] = t.y;                                  \
    wreg[4 * k + 2] = t.z; wreg[4 * k + 3] = t.w;                              \
  }                                                                            \
  const float bv = bias[lane];                                                 \
  float bsum = 0.0f, bsq = 0.0f;                                               \
  for (int j = 0; j < 32; ++j) { /* 32 rows per wave */                        \
    const int q = (gw << 5) + j;                                               \
    const float4* QUAL ip4 = (const float4*)(interp + (size_t)q * DD);         \
    float acc = 0.0f;                                                          \
    _Pragma("unroll")                                                          \
    for (int k = 0; k < DD / 4; ++k) {                                         \
      float4 t = ip4[k];                                                       \
      acc = __fmaf_rn(t.x, wreg[4 * k], acc);                                  \
      acc = __fmaf_rn(t.y, wreg[4 * k + 1], acc);                              \
      acc = __fmaf_rn(t.z, wreg[4 * k + 2], acc);                              \
      acc = __fmaf_rn(t.w, wreg[4 * k + 3], acc);                              \
    }                                                                          \
    float ov = __fadd_rn(acc, bv);                                             \
    out[(size_t)q * DD + lane] = ov;                                           \
    bsum = __fadd_rn(bsum, ov);                                                \
    bsq  = __fmaf_rn(ov, ov, bsq);                                             \
  }                                                                            \
  atomicAdd(&accum[lane], bsum);                                               \
  atomicAdd(&accum[DD + lane], bsq);

__global__ __launch_bounds__(256) void linear_bnstats_rq(
    const float* __restrict__ interp, const float* __restrict__ W,
    const float* __restrict__ bias, float* __restrict__ out,
    float* __restrict__ accum) {
  K3_BODY(__restrict__)
}

__global__ __launch_bounds__(256) void linear_bnstats_ma(
    const float* interp, const float* __restrict__ W,
    const float* __restrict__ bias, float* out,
    float* __restrict__ accum) {
  K3_BODY()
}

// K4: BatchNorm finalize; float4 per thread (HBM streaming, 32 MB).
__global__ __launch_bounds__(256) void bn_final(float* __restrict__ out,
                                                const float* __restrict__ accum,
                                                const float* __restrict__ gamma,
                                                const float* __restrict__ beta) {
  const int i4 = (int)blockIdx.x * 256 + (int)threadIdx.x;  // 1048576 float4s
  const int e0 = (i4 * 4) & 63;                             // 4 consecutive channels
  const float inv = 1.0f / (float)TQ;

  float4 v  = ((const float4*)out)[i4];
  float4 sm = *(const float4*)(accum + e0);
  float4 sq = *(const float4*)(accum + DD + e0);
  float4 g  = *(const float4*)(gamma + e0);
  float4 bt = *(const float4*)(beta + e0);

  float4 r;
  {
    float m = sm.x * inv, va = __fmaf_rn(-m, m, sq.x * inv);
    r.x = __fadd_rn(__fmul_rn(__fmul_rn(g.x, __fsub_rn(v.x, m)), rsqrtf(va + 1e-5f)), bt.x);
  }
  {
    float m = sm.y * inv, va = __fmaf_rn(-m, m, sq.y * inv);
    r.y = __fadd_rn(__fmul_rn(__fmul_rn(g.y, __fsub_rn(v.y, m)), rsqrtf(va + 1e-5f)), bt.y);
  }
  {
    float m = sm.z * inv, va = __fmaf_rn(-m, m, sq.z * inv);
    r.z = __fadd_rn(__fmul_rn(__fmul_rn(g.z, __fsub_rn(v.z, m)), rsqrtf(va + 1e-5f)), bt.z);
  }
  {
    float m = sm.w * inv, va = __fmaf_rn(-m, m, sq.w * inv);
    r.w = __fadd_rn(__fmul_rn(__fmul_rn(g.w, __fsub_rn(v.w, m)), rsqrtf(va + 1e-5f)), bt.w);
  }
  ((float4*)out)[i4] = r;
}

extern "C" void kernel_launch(void* const* d_in, const int* in_sizes, int n_in,
                              void* d_out, int out_size, void* d_ws, size_t ws_size,
                              hipStream_t stream) {
  const float* xyz1    = (const float*)d_in[0];
  const float* xyz2    = (const float*)d_in[1];
  // d_in[2] = points1 (unused in this module variant)
  const float* points2 = (const float*)d_in[3];
  const float* W       = (const float*)d_in[4];
  const float* bias    = (const float*)d_in[5];
  const float* gamma   = (const float*)d_in[6];
  const float* beta    = (const float*)d_in[7];
  float* out = (float*)d_out;

  // workspace carve-up (byte offsets, 16B-aligned):
  //   pts4   @ 0      : B*S float4   = 262144 B
  //   accum  @ 262144 : 128 floats   =    512 B
  //   interp @ 262656 : TQ*DD floats = 16 MiB   (if ws_size permits)
  char* ws = (char*)d_ws;
  float4* pts4 = (float4*)ws;
  float* accum = (float*)(ws + 262144);
  const size_t need = 262656 + (size_t)TQ * DD * sizeof(float);
  const bool ws_interp = (ws_size >= need);
  float* interp = ws_interp ? (float*)(ws + 262656) : out;

  prep<<<dim3((BB * SS) / 256), dim3(256), 0, stream>>>(xyz2, pts4, accum);
  // 4 threads per query: TQ*4/256 = 1024 blocks
  knn_interp<<<dim3((TQ * 4) / 256), dim3(256), 0, stream>>>(xyz1, pts4, points2, interp);
  // 512 blocks x 4 waves x 32 rows = 65536 rows
  if (ws_interp) {
    linear_bnstats_rq<<<dim3(TQ / 128), dim3(256), 0, stream>>>(interp, W, bias, out, accum);
  } else {
    linear_bnstats_ma<<<dim3(TQ / 128), dim3(256), 0, stream>>>(interp, W, bias, out, accum);
  }
  bn_final<<<dim3((TQ * DD) / (4 * 256)), dim3(256), 0, stream>>>(out, accum, gamma, beta);
}